// Round 3
// baseline (430.757 us; speedup 1.0000x reference)
//
#include <hip/hip_runtime.h>

#define TB 2
#define TT 2048
#define TDIM 2048
#define NHEADS 16
#define KVHEADS 4
#define HD 128

typedef unsigned short u16;
typedef __attribute__((ext_vector_type(8))) short short8;
typedef __attribute__((ext_vector_type(4))) float float4_t;

__device__ __forceinline__ float b2f(u16 u) {
    union { unsigned int i; float f; } v; v.i = ((unsigned int)u) << 16; return v.f;
}
__device__ __forceinline__ u16 f2b(float f) {
    union { float f; unsigned int i; } v; v.f = f;
    unsigned int r = (v.i + 0x7FFFu + ((v.i >> 16) & 1u)) >> 16;
    return (u16)r;
}

// ---------------------------------------------------------------------------
// bf16 GEMM: C[M,N] = A[M,K] * B[K,N], B pre-transposed (BT is N x K, bf16).
// 128x128 tile, BK=64, 4 waves (2x2). Manual uint4 staging, padded LDS rows
// (stride 72 u16 -> <=2-way bank alias, free per m136).
// F32OUT selects fp32 C (final projection) vs bf16 C (intermediates).
// ---------------------------------------------------------------------------
#define GLDA 72
template <bool F32OUT>
__global__ __launch_bounds__(256, 2)
void gemm_bt(const u16* __restrict__ A, const u16* __restrict__ BT,
             void* __restrict__ Cv, int M, int N, int K) {
    __shared__ __align__(16) u16 As[128 * GLDA];
    __shared__ __align__(16) u16 Bs[128 * GLDA];
    const int tid  = threadIdx.x;
    const int wave = tid >> 6, lane = tid & 63;
    const int quad = lane >> 4, l16 = lane & 15;
    const int wm = wave >> 1, wn = wave & 1;
    const int row0 = blockIdx.y * 128, col0 = blockIdx.x * 128;

    float4_t acc[4][4];
#pragma unroll
    for (int i = 0; i < 4; i++)
#pragma unroll
        for (int j = 0; j < 4; j++) acc[i][j] = (float4_t){0.f, 0.f, 0.f, 0.f};

    for (int kk = 0; kk < K; kk += 64) {
        __syncthreads();
#pragma unroll
        for (int i = 0; i < 4; i++) {
            int n = i * 256 + tid;
            int r = n >> 3, c = n & 7;
            *(uint4*)&As[r * GLDA + c * 8] =
                *(const uint4*)(A + (size_t)(row0 + r) * K + kk + c * 8);
            *(uint4*)&Bs[r * GLDA + c * 8] =
                *(const uint4*)(BT + (size_t)(col0 + r) * K + kk + c * 8);
        }
        __syncthreads();
#pragma unroll
        for (int ks = 0; ks < 2; ks++) {
            short8 af[4], bf[4];
#pragma unroll
            for (int mt = 0; mt < 4; mt++) {
                int m = wm * 64 + mt * 16 + l16;
                af[mt] = *(const short8*)&As[m * GLDA + (ks * 4 + quad) * 8];
            }
#pragma unroll
            for (int nt = 0; nt < 4; nt++) {
                int n = wn * 64 + nt * 16 + l16;
                bf[nt] = *(const short8*)&Bs[n * GLDA + (ks * 4 + quad) * 8];
            }
#pragma unroll
            for (int mt = 0; mt < 4; mt++)
#pragma unroll
                for (int nt = 0; nt < 4; nt++)
                    acc[mt][nt] = __builtin_amdgcn_mfma_f32_16x16x32_bf16(
                        af[mt], bf[nt], acc[mt][nt], 0, 0, 0);
        }
    }
    // epilogue: C/D layout col=lane&15, row=quad*4+reg  [m89/m91]
#pragma unroll
    for (int mt = 0; mt < 4; mt++)
#pragma unroll
        for (int nt = 0; nt < 4; nt++)
#pragma unroll
            for (int r = 0; r < 4; r++) {
                int row = row0 + wm * 64 + mt * 16 + quad * 4 + r;
                int col = col0 + wn * 64 + nt * 16 + l16;
                if (F32OUT)
                    ((float*)Cv)[(size_t)row * N + col] = acc[mt][nt][r];
                else
                    ((u16*)Cv)[(size_t)row * N + col] = f2b(acc[mt][nt][r]);
            }
}

// ---------------------------------------------------------------------------
// fp32 (rows x cols) -> bf16 transposed (cols x rows)
// ---------------------------------------------------------------------------
__global__ void cvt_transpose(const float* __restrict__ in, u16* __restrict__ out,
                              int rows, int cols) {
    __shared__ u16 tile[32][33];
    int c0 = blockIdx.x * 32, r0 = blockIdx.y * 32;
    int tx = threadIdx.x & 31, ty = threadIdx.x >> 5;
#pragma unroll
    for (int i = 0; i < 4; i++)
        tile[ty + i * 8][tx] = f2b(in[(size_t)(r0 + ty + i * 8) * cols + c0 + tx]);
    __syncthreads();
#pragma unroll
    for (int i = 0; i < 4; i++)
        out[(size_t)(c0 + ty + i * 8) * rows + r0 + tx] = tile[tx][ty + i * 8];
}

// fp32 -> bf16 elementwise, 4 elems/thread
__global__ void cvt_bf16(const float* __restrict__ in, u16* __restrict__ out) {
    size_t i = ((size_t)blockIdx.x * 256 + threadIdx.x) * 4;
    float4 v = *(const float4*)(in + i);
    ushort4 o;
    o.x = f2b(v.x); o.y = f2b(v.y); o.z = f2b(v.z); o.w = f2b(v.w);
    *(ushort4*)(out + i) = o;
}

// V slice of QKV (bf16, cols 2560 + kv*128) -> Vt[b][kv][d][t] (bf16)
__global__ void transpose_v(const u16* __restrict__ QKV, u16* __restrict__ Vt) {
    int z = blockIdx.z, b = z >> 2, kv = z & 3;
    const u16* in = QKV + (size_t)b * TT * 3072 + 2560 + kv * HD;  // (t,d)
    u16* out = Vt + (size_t)z * HD * TT;                           // (d,t)
    __shared__ u16 tile[32][33];
    int t0 = blockIdx.x * 32, d0 = blockIdx.y * 32;
    int tx = threadIdx.x & 31, ty = threadIdx.x >> 5;
#pragma unroll
    for (int i = 0; i < 4; i++)
        tile[ty + i * 8][tx] = in[(size_t)(t0 + ty + i * 8) * 3072 + d0 + tx];
    __syncthreads();
#pragma unroll
    for (int i = 0; i < 4; i++)
        out[(size_t)(d0 + ty + i * 8) * TT + t0 + tx] = tile[tx][ty + i * 8];
}

// ---------------------------------------------------------------------------
// RoPE in-place over a column slice of bf16 QKV. cos/sin are fp32 (T x 64).
// Each thread: 8 bf16 = 4 pairs.
// ---------------------------------------------------------------------------
__global__ void rope_k(u16* __restrict__ buf, const float* __restrict__ cosb,
                       const float* __restrict__ sinb, int colbase, int ncshift,
                       int rowstride) {
    size_t gid = (size_t)blockIdx.x * 256 + threadIdx.x;
    size_t e = gid * 8;
    int ncols = 1 << ncshift;
    int row = (int)(e >> ncshift);
    int col = (int)(e & (ncols - 1));
    int i0 = (col & (HD - 1)) >> 1;  // pair index within head, multiple of 4
    int t = row & (TT - 1);
    u16* p = buf + (size_t)row * rowstride + colbase + col;
    union { uint4 v; u16 u[8]; } d, o;
    d.v = *(const uint4*)p;
    float4 c4 = *(const float4*)(cosb + t * 64 + i0);
    float4 s4 = *(const float4*)(sinb + t * 64 + i0);
    float cc[4] = {c4.x, c4.y, c4.z, c4.w};
    float ss[4] = {s4.x, s4.y, s4.z, s4.w};
#pragma unroll
    for (int k = 0; k < 4; k++) {
        float re = b2f(d.u[2 * k]), im = b2f(d.u[2 * k + 1]);
        o.u[2 * k]     = f2b(re * cc[k] - im * ss[k]);
        o.u[2 * k + 1] = f2b(re * ss[k] + im * cc[k]);
    }
    *(uint4*)p = o.v;
}

// ---------------------------------------------------------------------------
// Causal flash attention (bf16). Block = 64 q-rows x one head; wave owns 16
// q-rows -> wave-local softmax. A-layout A[m=lane&15][k=quad*8+j];
// C/D col=lane&15,row=quad*4+reg. [m89/m120]
// ---------------------------------------------------------------------------
#define QLDA 136
#define VLDA 72
__global__ __launch_bounds__(256, 2)
void attn(const u16* __restrict__ QKV, const u16* __restrict__ Vt,
          u16* __restrict__ O) {
    const int qb = blockIdx.x;      // q tile 0..31
    const int h  = blockIdx.y;      // head
    const int b  = blockIdx.z;      // batch
    const int kv = h >> 2;
    const int tid = threadIdx.x, wave = tid >> 6, lane = tid & 63;
    const int quad = lane >> 4, l16 = lane & 15;

    __shared__ __align__(16) u16 Qs[64 * QLDA];    // [qrow][d]
    __shared__ __align__(16) u16 Ks[64 * QLDA];    // [key][d]
    __shared__ __align__(16) u16 Vs[128 * VLDA];   // [d][key]
    __shared__ __align__(16) short Ps[4][16 * 72]; // wave-private P strip

    const u16* Qbase = QKV + ((size_t)b * TT + qb * 64) * 3072 + h * HD;
    const u16* Kbase = QKV + (size_t)b * TT * 3072 + 2048 + kv * HD;
    const u16* Vbase = Vt + (size_t)(b * 4 + kv) * HD * TT;

    // stage Q tile once: 64 rows x 16 chunks
#pragma unroll
    for (int i = 0; i < 4; i++) {
        int n = i * 256 + tid;
        int r = n >> 4, c = n & 15;
        *(uint4*)&Qs[r * QLDA + c * 8] =
            *(const uint4*)(Qbase + (size_t)r * 3072 + c * 8);
    }

    float4_t o[8];
#pragma unroll
    for (int i = 0; i < 8; i++) o[i] = (float4_t){0.f, 0.f, 0.f, 0.f};
    float mi[4], li[4];
#pragma unroll
    for (int r = 0; r < 4; r++) { mi[r] = -1e30f; li[r] = 0.f; }

    const float scale = 0.08838834764831843f;  // 1/sqrt(128)

    for (int kt = 0; kt <= qb; kt++) {
        __syncthreads();
#pragma unroll
        for (int i = 0; i < 4; i++) {
            int n = i * 256 + tid;
            int r = n >> 4, c = n & 15;
            *(uint4*)&Ks[r * QLDA + c * 8] =
                *(const uint4*)(Kbase + (size_t)(kt * 64 + r) * 3072 + c * 8);
        }
#pragma unroll
        for (int i = 0; i < 4; i++) {
            int n = i * 256 + tid;
            int d = n >> 3, c = n & 7;
            *(uint4*)&Vs[d * VLDA + c * 8] =
                *(const uint4*)(Vbase + (size_t)d * TT + kt * 64 + c * 8);
        }
        __syncthreads();

        // S = Q K^T for this wave's 16 q-rows x 64 keys
        float4_t st[4];
#pragma unroll
        for (int nt = 0; nt < 4; nt++) st[nt] = (float4_t){0.f, 0.f, 0.f, 0.f};
#pragma unroll
        for (int ks = 0; ks < 4; ks++) {
            int mq = wave * 16 + l16;
            short8 aq = *(const short8*)&Qs[mq * QLDA + (ks * 4 + quad) * 8];
#pragma unroll
            for (int nt = 0; nt < 4; nt++) {
                int kr = nt * 16 + l16;
                short8 bk = *(const short8*)&Ks[kr * QLDA + (ks * 4 + quad) * 8];
                st[nt] = __builtin_amdgcn_mfma_f32_16x16x32_bf16(aq, bk, st[nt], 0, 0, 0);
            }
        }

        // scale + causal mask
        const int qrow0 = qb * 64 + wave * 16 + quad * 4;  // + r
        const bool diag = (kt == qb);
        float p[4][4];
#pragma unroll
        for (int nt = 0; nt < 4; nt++) {
            int key = kt * 64 + nt * 16 + l16;
#pragma unroll
            for (int r = 0; r < 4; r++) {
                float s = st[nt][r] * scale;
                if (diag && key > qrow0 + r) s = -1e30f;
                p[nt][r] = s;
            }
        }
        // online softmax (rows live in the lane&15 shuffle group)
        float mnew[4], alpha[4];
#pragma unroll
        for (int r = 0; r < 4; r++) {
            float rm = fmaxf(fmaxf(p[0][r], p[1][r]), fmaxf(p[2][r], p[3][r]));
            rm = fmaxf(rm, __shfl_xor(rm, 1, 64));
            rm = fmaxf(rm, __shfl_xor(rm, 2, 64));
            rm = fmaxf(rm, __shfl_xor(rm, 4, 64));
            rm = fmaxf(rm, __shfl_xor(rm, 8, 64));
            mnew[r] = fmaxf(mi[r], rm);
            alpha[r] = __expf(mi[r] - mnew[r]);
            mi[r] = mnew[r];
        }
#pragma unroll
        for (int r = 0; r < 4; r++) {
            float rs = 0.f;
#pragma unroll
            for (int nt = 0; nt < 4; nt++) {
                float e = __expf(p[nt][r] - mnew[r]);
                p[nt][r] = e;
                rs += e;
            }
            rs += __shfl_xor(rs, 1, 64);
            rs += __shfl_xor(rs, 2, 64);
            rs += __shfl_xor(rs, 4, 64);
            rs += __shfl_xor(rs, 8, 64);
            li[r] = li[r] * alpha[r] + rs;
        }
        // write P (C-layout) to wave-private LDS strip; rescale O
#pragma unroll
        for (int nt = 0; nt < 4; nt++)
#pragma unroll
            for (int r = 0; r < 4; r++)
                Ps[wave][(quad * 4 + r) * 72 + nt * 16 + l16] = (short)f2b(p[nt][r]);
#pragma unroll
        for (int n2 = 0; n2 < 8; n2++)
#pragma unroll
            for (int r = 0; r < 4; r++) o[n2][r] *= alpha[r];

        // O += P * V  (A-frag from Ps, B-frag from Vs = V^T)
#pragma unroll
        for (int ks2 = 0; ks2 < 2; ks2++) {
            short8 ap = *(const short8*)&Ps[wave][l16 * 72 + ks2 * 32 + quad * 8];
#pragma unroll
            for (int n2 = 0; n2 < 8; n2++) {
                int d = n2 * 16 + l16;
                short8 bv = *(const short8*)&Vs[d * VLDA + (ks2 * 4 + quad) * 8];
                o[n2] = __builtin_amdgcn_mfma_f32_16x16x32_bf16(ap, bv, o[n2], 0, 0, 0);
            }
        }
    }

    // epilogue: O[b*T + qb*64 + row][h*128 + col] = o / l
    u16* Obase = O + ((size_t)b * TT + qb * 64) * TDIM + h * HD;
#pragma unroll
    for (int n2 = 0; n2 < 8; n2++)
#pragma unroll
        for (int r = 0; r < 4; r++) {
            int row = wave * 16 + quad * 4 + r;
            int col = n2 * 16 + l16;
            Obase[(size_t)row * TDIM + col] = f2b(o[n2][r] / li[r]);
        }
}

// ---------------------------------------------------------------------------
extern "C" void kernel_launch(void* const* d_in, const int* in_sizes, int n_in,
                              void* d_out, int out_size, void* d_ws, size_t ws_size,
                              hipStream_t stream) {
    const float* x  = (const float*)d_in[0];
    const float* fc = (const float*)d_in[1];
    const float* fs = (const float*)d_in[2];
    const float* wq = (const float*)d_in[3];
    const float* wk = (const float*)d_in[4];
    const float* wv = (const float*)d_in[5];
    const float* wo = (const float*)d_in[6];
    float* out = (float*)d_out;

    char* ws = (char*)d_ws;
    size_t off = 0;
    auto alloc = [&](size_t bytes) -> void* {
        void* p = ws + off;
        off += (bytes + 255) & ~(size_t)255;
        return p;
    };
    u16* xb  = (u16*)alloc((size_t)4096 * 2048 * 2);  // x in bf16
    u16* WT  = (u16*)alloc((size_t)3072 * 2048 * 2);  // [wqT | wkT | wvT], N x K bf16
    u16* woT = (u16*)alloc((size_t)2048 * 2048 * 2);
    u16* QKV = (u16*)alloc((size_t)4096 * 3072 * 2);  // [Q | K | V] fused bf16
    u16* Vtb = (u16*)alloc((size_t)4096 * 512 * 2);   // V^T per (b,kv): [d][t]
    u16* Ob  = (u16*)alloc((size_t)4096 * 2048 * 2);  // attention output bf16

    dim3 blk(256);
    // ingest: fp32 -> bf16 (weights transposed to N x K)
    cvt_bf16<<<dim3(8192), blk, 0, stream>>>(x, xb);
    cvt_transpose<<<dim3(64, 64), blk, 0, stream>>>(wq, WT, 2048, 2048);
    cvt_transpose<<<dim3(16, 64), blk, 0, stream>>>(wk, WT + (size_t)2048 * 2048, 2048, 512);
    cvt_transpose<<<dim3(16, 64), blk, 0, stream>>>(wv, WT + (size_t)2560 * 2048, 2048, 512);
    cvt_transpose<<<dim3(64, 64), blk, 0, stream>>>(wo, woT, 2048, 2048);
    // fused QKV projection: (4096 x 2048) @ (2048 x 3072), bf16 out
    gemm_bt<false><<<dim3(24, 32), blk, 0, stream>>>(xb, WT, QKV, 4096, 3072, 2048);
    // RoPE on Q (cols 0..2047) and K (cols 2048..2559); cos/sin fp32
    rope_k<<<dim3(4096), blk, 0, stream>>>(QKV, fc, fs, 0, 11, 3072);
    rope_k<<<dim3(1024), blk, 0, stream>>>(QKV, fc, fs, 2048, 9, 3072);
    // V transpose for attention B-operand
    transpose_v<<<dim3(64, 4, 8), blk, 0, stream>>>(QKV, Vtb);
    // causal flash attention
    attn<<<dim3(32, 16, 2), blk, 0, stream>>>(QKV, Vtb, Ob);
    // output projection: (4096 x 2048) @ (2048 x 2048), fp32 out
    gemm_bt<true><<<dim3(16, 32), blk, 0, stream>>>(Ob, woT, out, 4096, 2048, 2048);
}

// Round 4
// 316.268 us; speedup vs baseline: 1.3620x; 1.3620x over previous
//
#include <hip/hip_runtime.h>

#define TB 2
#define TT 2048
#define TDIM 2048
#define NHEADS 16
#define KVHEADS 4
#define HD 128

typedef unsigned short u16;
typedef unsigned int u32;
typedef __attribute__((ext_vector_type(8))) short short8;
typedef __attribute__((ext_vector_type(4))) float float4_t;

__device__ __forceinline__ float b2f(u16 u) {
    union { u32 i; float f; } v; v.i = ((u32)u) << 16; return v.f;
}
__device__ __forceinline__ u16 f2b(float f) {
    union { float f; u32 i; } v; v.f = f;
    u32 r = (v.i + 0x7FFFu + ((v.i >> 16) & 1u)) >> 16;
    return (u16)r;
}

// async global->LDS, 16B/lane; LDS dest must be wave-uniform base (+lane*16)
__device__ __forceinline__ void gl_lds16(const void* g, void* l) {
    __builtin_amdgcn_global_load_lds((const __attribute__((address_space(1))) void*)g,
                                     (__attribute__((address_space(3))) void*)l, 16, 0, 0);
}

// ---------------------------------------------------------------------------
// bf16 GEMM: C[M,N] = A[M,K] * B[K,N], B pre-transposed (BT is N x K, bf16).
// 128x128 tile, BK=64, 4 waves (2x2). m97 structure: global_load_lds width-16
// staging, contiguous [row][8-chunk] LDS with XOR swizzle slot = c ^ (r&7)
// (involution; spreads frag-read banks across l16).
// ---------------------------------------------------------------------------
template <bool F32OUT>
__global__ __launch_bounds__(256, 3)
void gemm_bt(const u16* __restrict__ A, const u16* __restrict__ BT,
             void* __restrict__ Cv, int M, int N, int K) {
    __shared__ __align__(16) u16 As[128 * 64];
    __shared__ __align__(16) u16 Bs[128 * 64];
    const int tid  = threadIdx.x;
    const int wave = tid >> 6, lane = tid & 63;
    const int quad = lane >> 4, l16 = lane & 15;
    const int wm = wave >> 1, wn = wave & 1;
    const int row0 = blockIdx.y * 128, col0 = blockIdx.x * 128;

    float4_t acc[4][4];
#pragma unroll
    for (int i = 0; i < 4; i++)
#pragma unroll
        for (int j = 0; j < 4; j++) acc[i][j] = (float4_t){0.f, 0.f, 0.f, 0.f};

    for (int kk = 0; kk < K; kk += 64) {
        __syncthreads();
        // stage A (128x64) and BT (128x64): 1024 chunks each, swizzled
#pragma unroll
        for (int i = 0; i < 4; i++) {
            int n = i * 256 + wave * 64 + lane;
            int r = n >> 3, c = (n & 7) ^ (r & 7);
            gl_lds16(A  + (size_t)(row0 + r) * K + kk + c * 8, &As[(i * 256 + wave * 64) * 8]);
            gl_lds16(BT + (size_t)(col0 + r) * K + kk + c * 8, &Bs[(i * 256 + wave * 64) * 8]);
        }
        __syncthreads();
#pragma unroll
        for (int ks = 0; ks < 2; ks++) {
            short8 af[4], bf[4];
#pragma unroll
            for (int mt = 0; mt < 4; mt++) {
                int m = wm * 64 + mt * 16 + l16;
                af[mt] = *(const short8*)&As[(m * 8 + ((ks * 4 + quad) ^ (l16 & 7))) * 8];
            }
#pragma unroll
            for (int nt = 0; nt < 4; nt++) {
                int n = wn * 64 + nt * 16 + l16;
                bf[nt] = *(const short8*)&Bs[(n * 8 + ((ks * 4 + quad) ^ (l16 & 7))) * 8];
            }
#pragma unroll
            for (int mt = 0; mt < 4; mt++)
#pragma unroll
                for (int nt = 0; nt < 4; nt++)
                    acc[mt][nt] = __builtin_amdgcn_mfma_f32_16x16x32_bf16(
                        af[mt], bf[nt], acc[mt][nt], 0, 0, 0);
        }
    }
    // epilogue: C/D layout col=lane&15, row=quad*4+reg  [m89/m91]
#pragma unroll
    for (int mt = 0; mt < 4; mt++)
#pragma unroll
        for (int nt = 0; nt < 4; nt++)
#pragma unroll
            for (int r = 0; r < 4; r++) {
                int row = row0 + wm * 64 + mt * 16 + quad * 4 + r;
                int col = col0 + wn * 64 + nt * 16 + l16;
                if (F32OUT)
                    ((float*)Cv)[(size_t)row * N + col] = acc[mt][nt][r];
                else
                    ((u16*)Cv)[(size_t)row * N + col] = f2b(acc[mt][nt][r]);
            }
}

// ---------------------------------------------------------------------------
// fp32 (rows x cols) -> bf16 transposed (cols x rows)
// ---------------------------------------------------------------------------
__global__ void cvt_transpose(const float* __restrict__ in, u16* __restrict__ out,
                              int rows, int cols) {
    __shared__ u16 tile[32][33];
    int c0 = blockIdx.x * 32, r0 = blockIdx.y * 32;
    int tx = threadIdx.x & 31, ty = threadIdx.x >> 5;
#pragma unroll
    for (int i = 0; i < 4; i++)
        tile[ty + i * 8][tx] = f2b(in[(size_t)(r0 + ty + i * 8) * cols + c0 + tx]);
    __syncthreads();
#pragma unroll
    for (int i = 0; i < 4; i++)
        out[(size_t)(c0 + ty + i * 8) * rows + r0 + tx] = tile[tx][ty + i * 8];
}

// fp32 -> bf16 elementwise, 4 elems/thread
__global__ void cvt_bf16(const float* __restrict__ in, u16* __restrict__ out) {
    size_t i = ((size_t)blockIdx.x * 256 + threadIdx.x) * 4;
    float4 v = *(const float4*)(in + i);
    ushort4 o;
    o.x = f2b(v.x); o.y = f2b(v.y); o.z = f2b(v.z); o.w = f2b(v.w);
    *(ushort4*)(out + i) = o;
}

// V slice of QKV (bf16, cols 2560 + kv*128) -> Vt[b][kv][d][t] (bf16)
__global__ void transpose_v(const u16* __restrict__ QKV, u16* __restrict__ Vt) {
    int z = blockIdx.z, b = z >> 2, kv = z & 3;
    const u16* in = QKV + (size_t)b * TT * 3072 + 2560 + kv * HD;  // (t,d)
    u16* out = Vt + (size_t)z * HD * TT;                           // (d,t)
    __shared__ u16 tile[32][33];
    int t0 = blockIdx.x * 32, d0 = blockIdx.y * 32;
    int tx = threadIdx.x & 31, ty = threadIdx.x >> 5;
#pragma unroll
    for (int i = 0; i < 4; i++)
        tile[ty + i * 8][tx] = in[(size_t)(t0 + ty + i * 8) * 3072 + d0 + tx];
    __syncthreads();
#pragma unroll
    for (int i = 0; i < 4; i++)
        out[(size_t)(d0 + ty + i * 8) * TT + t0 + tx] = tile[tx][ty + i * 8];
}

// ---------------------------------------------------------------------------
// RoPE in-place over a column slice of bf16 QKV. cos/sin fp32 (T x 64).
// ---------------------------------------------------------------------------
__global__ void rope_k(u16* __restrict__ buf, const float* __restrict__ cosb,
                       const float* __restrict__ sinb, int colbase, int ncshift,
                       int rowstride) {
    size_t gid = (size_t)blockIdx.x * 256 + threadIdx.x;
    size_t e = gid * 8;
    int ncols = 1 << ncshift;
    int row = (int)(e >> ncshift);
    int col = (int)(e & (ncols - 1));
    int i0 = (col & (HD - 1)) >> 1;
    int t = row & (TT - 1);
    u16* p = buf + (size_t)row * rowstride + colbase + col;
    union { uint4 v; u16 u[8]; } d, o;
    d.v = *(const uint4*)p;
    float4 c4 = *(const float4*)(cosb + t * 64 + i0);
    float4 s4 = *(const float4*)(sinb + t * 64 + i0);
    float cc[4] = {c4.x, c4.y, c4.z, c4.w};
    float ss[4] = {s4.x, s4.y, s4.z, s4.w};
#pragma unroll
    for (int k = 0; k < 4; k++) {
        float re = b2f(d.u[2 * k]), im = b2f(d.u[2 * k + 1]);
        o.u[2 * k]     = f2b(re * cc[k] - im * ss[k]);
        o.u[2 * k + 1] = f2b(re * ss[k] + im * cc[k]);
    }
    *(uint4*)p = o.v;
}

// ---------------------------------------------------------------------------
// Causal flash attention v2. Block = 4 waves; each wave owns 16 q-rows of a
// 64-row q-tile. Block processes q-tiles (g) then (31-g): uniform 33 k-tiles.
// S^T = K·Q^T: A-frag = K rows (LDS, swizzled), B-frag = Q rows (REGISTERS).
// S^T C-layout: col(lane&15)=q-row, row(quad*4+r)=key -> softmax reduce =
// 2 shfls across quads; P-write = 4x ds_write_b64 into wave-private padded
// strip; PV: A-frag from strip rows (q=l16), B-frag = V^T rows (d) from LDS.
// ---------------------------------------------------------------------------
#define PSTR 72
__global__ __launch_bounds__(256, 3)
void attn(const u16* __restrict__ QKV, const u16* __restrict__ Vt,
          u16* __restrict__ O) {
    const int g = blockIdx.x;       // pair index 0..15
    const int h = blockIdx.y;       // head
    const int b = blockIdx.z;       // batch
    const int kvh = h >> 2;
    const int tid = threadIdx.x, w = tid >> 6, lane = tid & 63;
    const int quad = lane >> 4, l16 = lane & 15;

    __shared__ __align__(16) u16 Ks[64 * 128];      // [key][16 chunks] sw: c^(key&15)
    __shared__ __align__(16) u16 Vs[128 * 64];      // [d][8 chunks]    sw: c^(d&7)
    __shared__ __align__(16) u16 Ps[4][16 * PSTR];  // wave-private [q=l16][64 keys]

    const u16* Kbase = QKV + (size_t)b * TT * 3072 + 2048 + kvh * HD;
    const u16* Vbase = Vt + (size_t)(b * 4 + kvh) * HD * TT;
    const float scale = 0.08838834764831843f;  // 1/sqrt(128)

    for (int ph = 0; ph < 2; ph++) {
        const int qb = ph ? (31 - g) : g;
        // Q fragments to registers (B-layout: lane l16 = q-row, quad*8+j = k)
        const u16* Qrow = QKV + ((size_t)b * TT + qb * 64 + w * 16 + l16) * 3072 + h * HD;
        short8 qf[4];
#pragma unroll
        for (int ks = 0; ks < 4; ks++)
            qf[ks] = *(const short8*)(Qrow + ks * 32 + quad * 8);

        float4_t o[8];
#pragma unroll
        for (int i = 0; i < 8; i++) o[i] = (float4_t){0.f, 0.f, 0.f, 0.f};
        float mi = -1e30f, li = 0.f;
        const int qg = qb * 64 + w * 16 + l16;  // this lane's q-row (S^T col)

        for (int kt = 0; kt <= qb; kt++) {
            __syncthreads();
            // stage K tile (64x128) and V^T tile (128x64), swizzled chunks
#pragma unroll
            for (int i = 0; i < 4; i++) {
                int n = i * 256 + w * 64 + lane;
                int r = n >> 4, c = (n & 15) ^ (r & 15);
                gl_lds16(Kbase + (size_t)(kt * 64 + r) * 3072 + c * 8,
                         &Ks[(i * 256 + w * 64) * 8]);
            }
#pragma unroll
            for (int i = 0; i < 4; i++) {
                int n = i * 256 + w * 64 + lane;
                int d = n >> 3, c = (n & 7) ^ (d & 7);
                gl_lds16(Vbase + (size_t)d * TT + kt * 64 + c * 8,
                         &Vs[(i * 256 + w * 64) * 8]);
            }
            __syncthreads();

            // S^T = K·Q^T : D[key][q], 64 keys x 16 q
            float4_t st[4];
#pragma unroll
            for (int nt = 0; nt < 4; nt++) st[nt] = (float4_t){0.f, 0.f, 0.f, 0.f};
#pragma unroll
            for (int ks = 0; ks < 4; ks++) {
                short8 af[4];
#pragma unroll
                for (int nt = 0; nt < 4; nt++)
                    af[nt] = *(const short8*)&Ks[((nt * 16 + l16) * 16 +
                                                  ((ks * 4 + quad) ^ l16)) * 8];
#pragma unroll
                for (int nt = 0; nt < 4; nt++)
                    st[nt] = __builtin_amdgcn_mfma_f32_16x16x32_bf16(
                        af[nt], qf[ks], st[nt], 0, 0, 0);
            }

            // scale + causal mask (only diag tile needs it); lane's q = qg
            const bool diag = (kt == qb);
            float pm = -1e30f;
#pragma unroll
            for (int nt = 0; nt < 4; nt++)
#pragma unroll
                for (int r = 0; r < 4; r++) {
                    float v = st[nt][r] * scale;
                    int key = kt * 64 + nt * 16 + quad * 4 + r;
                    if (diag && key > qg) v = -1e30f;
                    st[nt][r] = v;
                    pm = fmaxf(pm, v);
                }
            // row reduce across quads (lanes l16, +16, +32, +48)
            pm = fmaxf(pm, __shfl_xor(pm, 16, 64));
            pm = fmaxf(pm, __shfl_xor(pm, 32, 64));
            float mnew = fmaxf(mi, pm);
            float alpha = __expf(mi - mnew);
            mi = mnew;
            float rs = 0.f;
#pragma unroll
            for (int nt = 0; nt < 4; nt++)
#pragma unroll
                for (int r = 0; r < 4; r++) {
                    float e = __expf(st[nt][r] - mnew);
                    st[nt][r] = e;
                    rs += e;
                }
            rs += __shfl_xor(rs, 16, 64);
            rs += __shfl_xor(rs, 32, 64);
            li = li * alpha + rs;

            // P -> wave-private strip: row q=l16, keys nt*16+quad*4..+3 (b64)
#pragma unroll
            for (int nt = 0; nt < 4; nt++) {
                uint2 pk;
                pk.x = (u32)f2b(st[nt][0]) | ((u32)f2b(st[nt][1]) << 16);
                pk.y = (u32)f2b(st[nt][2]) | ((u32)f2b(st[nt][3]) << 16);
                *(uint2*)&Ps[w][l16 * PSTR + nt * 16 + quad * 4] = pk;
            }
            // rescale O (o rows are q=quad*4+r -> fetch alpha from lane q)
            float a_o[4];
#pragma unroll
            for (int r = 0; r < 4; r++) a_o[r] = __shfl(alpha, quad * 4 + r, 64);
#pragma unroll
            for (int n2 = 0; n2 < 8; n2++)
#pragma unroll
                for (int r = 0; r < 4; r++) o[n2][r] *= a_o[r];

            // O += P·V : A-frag from strip (m=q=l16), B-frag = V^T rows (n=d)
#pragma unroll
            for (int ks2 = 0; ks2 < 2; ks2++) {
                short8 ap = *(const short8*)&Ps[w][l16 * PSTR + ks2 * 32 + quad * 8];
#pragma unroll
                for (int n2 = 0; n2 < 8; n2++) {
                    short8 bv = *(const short8*)&Vs[((n2 * 16 + l16) * 8 +
                                                     ((ks2 * 4 + quad) ^ (l16 & 7))) * 8];
                    o[n2] = __builtin_amdgcn_mfma_f32_16x16x32_bf16(ap, bv, o[n2], 0, 0, 0);
                }
            }
        }

        // epilogue: rows quad*4+r of this wave's 16; li from lane q
        float l_o[4];
#pragma unroll
        for (int r = 0; r < 4; r++) l_o[r] = __shfl(li, quad * 4 + r, 64);
        u16* Ob2 = O + ((size_t)b * TT + qb * 64 + w * 16) * TDIM + h * HD;
#pragma unroll
        for (int n2 = 0; n2 < 8; n2++)
#pragma unroll
            for (int r = 0; r < 4; r++)
                Ob2[(size_t)(quad * 4 + r) * TDIM + n2 * 16 + l16] =
                    f2b(o[n2][r] / l_o[r]);
    }
}

// ---------------------------------------------------------------------------
extern "C" void kernel_launch(void* const* d_in, const int* in_sizes, int n_in,
                              void* d_out, int out_size, void* d_ws, size_t ws_size,
                              hipStream_t stream) {
    const float* x  = (const float*)d_in[0];
    const float* fc = (const float*)d_in[1];
    const float* fs = (const float*)d_in[2];
    const float* wq = (const float*)d_in[3];
    const float* wk = (const float*)d_in[4];
    const float* wv = (const float*)d_in[5];
    const float* wo = (const float*)d_in[6];
    float* out = (float*)d_out;

    char* ws = (char*)d_ws;
    size_t off = 0;
    auto alloc = [&](size_t bytes) -> void* {
        void* p = ws + off;
        off += (bytes + 255) & ~(size_t)255;
        return p;
    };
    u16* xb  = (u16*)alloc((size_t)4096 * 2048 * 2);  // x in bf16
    u16* WT  = (u16*)alloc((size_t)3072 * 2048 * 2);  // [wqT|wkT|wvT] N x K bf16
    u16* woT = (u16*)alloc((size_t)2048 * 2048 * 2);
    u16* QKV = (u16*)alloc((size_t)4096 * 3072 * 2);  // [Q|K|V] fused bf16
    u16* Vtb = (u16*)alloc((size_t)4096 * 512 * 2);   // V^T per (b,kv): [d][t]
    u16* Ob  = (u16*)alloc((size_t)4096 * 2048 * 2);  // attention output bf16

    dim3 blk(256);
    cvt_bf16<<<dim3(8192), blk, 0, stream>>>(x, xb);
    cvt_transpose<<<dim3(64, 64), blk, 0, stream>>>(wq, WT, 2048, 2048);
    cvt_transpose<<<dim3(16, 64), blk, 0, stream>>>(wk, WT + (size_t)2048 * 2048, 2048, 512);
    cvt_transpose<<<dim3(16, 64), blk, 0, stream>>>(wv, WT + (size_t)2560 * 2048, 2048, 512);
    cvt_transpose<<<dim3(64, 64), blk, 0, stream>>>(wo, woT, 2048, 2048);
    gemm_bt<false><<<dim3(24, 32), blk, 0, stream>>>(xb, WT, QKV, 4096, 3072, 2048);
    rope_k<<<dim3(4096), blk, 0, stream>>>(QKV, fc, fs, 0, 11, 3072);
    rope_k<<<dim3(1024), blk, 0, stream>>>(QKV, fc, fs, 2048, 9, 3072);
    transpose_v<<<dim3(64, 4, 8), blk, 0, stream>>>(QKV, Vtb);
    attn<<<dim3(16, 16, 2), blk, 0, stream>>>(QKV, Vtb, Ob);
    gemm_bt<true><<<dim3(16, 32), blk, 0, stream>>>(Ob, woT, out, 4096, 2048, 2048);
}

// Round 5
// 300.384 us; speedup vs baseline: 1.4340x; 1.0529x over previous
//
#include <hip/hip_runtime.h>

#define TB 2
#define TT 2048
#define TDIM 2048
#define NHEADS 16
#define KVHEADS 4
#define HD 128

typedef unsigned short u16;
typedef unsigned int u32;
typedef __attribute__((ext_vector_type(8))) short short8;
typedef __attribute__((ext_vector_type(4))) float float4_t;

__device__ __forceinline__ float b2f(u16 u) {
    union { u32 i; float f; } v; v.i = ((u32)u) << 16; return v.f;
}
__device__ __forceinline__ u16 f2b(float f) {
    union { float f; u32 i; } v; v.f = f;
    u32 r = (v.i + 0x7FFFu + ((v.i >> 16) & 1u)) >> 16;
    return (u16)r;
}
__device__ __forceinline__ u32 fbits(float f) {
    union { float f; u32 i; } v; v.f = f; return v.i;
}

// async global->LDS, 16B/lane; LDS dest must be wave-uniform base (+lane*16)
__device__ __forceinline__ void gl_lds16(const void* g, void* l) {
    __builtin_amdgcn_global_load_lds((const __attribute__((address_space(1))) void*)g,
                                     (__attribute__((address_space(3))) void*)l, 16, 0, 0);
}

// ---------------------------------------------------------------------------
// bf16 GEMM: C[M,N] = A[M,K] * B[K,N], B pre-transposed (BT is N x K, bf16).
// 128x128 tile, BK=64, 4 waves (2x2). m97 structure (unchanged this round).
// ---------------------------------------------------------------------------
template <bool F32OUT>
__global__ __launch_bounds__(256, 3)
void gemm_bt(const u16* __restrict__ A, const u16* __restrict__ BT,
             void* __restrict__ Cv, int M, int N, int K) {
    __shared__ __align__(16) u16 As[128 * 64];
    __shared__ __align__(16) u16 Bs[128 * 64];
    const int tid  = threadIdx.x;
    const int wave = tid >> 6, lane = tid & 63;
    const int quad = lane >> 4, l16 = lane & 15;
    const int wm = wave >> 1, wn = wave & 1;
    const int row0 = blockIdx.y * 128, col0 = blockIdx.x * 128;

    float4_t acc[4][4];
#pragma unroll
    for (int i = 0; i < 4; i++)
#pragma unroll
        for (int j = 0; j < 4; j++) acc[i][j] = (float4_t){0.f, 0.f, 0.f, 0.f};

    for (int kk = 0; kk < K; kk += 64) {
        __syncthreads();
#pragma unroll
        for (int i = 0; i < 4; i++) {
            int n = i * 256 + wave * 64 + lane;
            int r = n >> 3, c = (n & 7) ^ (r & 7);
            gl_lds16(A  + (size_t)(row0 + r) * K + kk + c * 8, &As[(i * 256 + wave * 64) * 8]);
            gl_lds16(BT + (size_t)(col0 + r) * K + kk + c * 8, &Bs[(i * 256 + wave * 64) * 8]);
        }
        __syncthreads();
#pragma unroll
        for (int ks = 0; ks < 2; ks++) {
            short8 af[4], bf[4];
#pragma unroll
            for (int mt = 0; mt < 4; mt++) {
                int m = wm * 64 + mt * 16 + l16;
                af[mt] = *(const short8*)&As[(m * 8 + ((ks * 4 + quad) ^ (l16 & 7))) * 8];
            }
#pragma unroll
            for (int nt = 0; nt < 4; nt++) {
                int n = wn * 64 + nt * 16 + l16;
                bf[nt] = *(const short8*)&Bs[(n * 8 + ((ks * 4 + quad) ^ (l16 & 7))) * 8];
            }
#pragma unroll
            for (int mt = 0; mt < 4; mt++)
#pragma unroll
                for (int nt = 0; nt < 4; nt++)
                    acc[mt][nt] = __builtin_amdgcn_mfma_f32_16x16x32_bf16(
                        af[mt], bf[nt], acc[mt][nt], 0, 0, 0);
        }
    }
    // epilogue: C/D layout col=lane&15, row=quad*4+reg  [m89/m91]
#pragma unroll
    for (int mt = 0; mt < 4; mt++)
#pragma unroll
        for (int nt = 0; nt < 4; nt++)
#pragma unroll
            for (int r = 0; r < 4; r++) {
                int row = row0 + wm * 64 + mt * 16 + quad * 4 + r;
                int col = col0 + wn * 64 + nt * 16 + l16;
                if (F32OUT)
                    ((float*)Cv)[(size_t)row * N + col] = acc[mt][nt][r];
                else
                    ((u16*)Cv)[(size_t)row * N + col] = f2b(acc[mt][nt][r]);
            }
}

// ---------------------------------------------------------------------------
// fp32 (rows x cols) -> bf16 transposed (cols x rows)
// ---------------------------------------------------------------------------
__global__ void cvt_transpose(const float* __restrict__ in, u16* __restrict__ out,
                              int rows, int cols) {
    __shared__ u16 tile[32][33];
    int c0 = blockIdx.x * 32, r0 = blockIdx.y * 32;
    int tx = threadIdx.x & 31, ty = threadIdx.x >> 5;
#pragma unroll
    for (int i = 0; i < 4; i++)
        tile[ty + i * 8][tx] = f2b(in[(size_t)(r0 + ty + i * 8) * cols + c0 + tx]);
    __syncthreads();
#pragma unroll
    for (int i = 0; i < 4; i++)
        out[(size_t)(c0 + ty + i * 8) * rows + r0 + tx] = tile[tx][ty + i * 8];
}

// fp32 -> bf16 elementwise, 4 elems/thread
__global__ void cvt_bf16(const float* __restrict__ in, u16* __restrict__ out) {
    size_t i = ((size_t)blockIdx.x * 256 + threadIdx.x) * 4;
    float4 v = *(const float4*)(in + i);
    ushort4 o;
    o.x = f2b(v.x); o.y = f2b(v.y); o.z = f2b(v.z); o.w = f2b(v.w);
    *(ushort4*)(out + i) = o;
}

// V slice of QKV (bf16, cols 2560 + kv*128) -> Vt[b][kv][d][t] (bf16)
__global__ void transpose_v(const u16* __restrict__ QKV, u16* __restrict__ Vt) {
    int z = blockIdx.z, b = z >> 2, kv = z & 3;
    const u16* in = QKV + (size_t)b * TT * 3072 + 2560 + kv * HD;  // (t,d)
    u16* out = Vt + (size_t)z * HD * TT;                           // (d,t)
    __shared__ u16 tile[32][33];
    int t0 = blockIdx.x * 32, d0 = blockIdx.y * 32;
    int tx = threadIdx.x & 31, ty = threadIdx.x >> 5;
#pragma unroll
    for (int i = 0; i < 4; i++)
        tile[ty + i * 8][tx] = in[(size_t)(t0 + ty + i * 8) * 3072 + d0 + tx];
    __syncthreads();
#pragma unroll
    for (int i = 0; i < 4; i++)
        out[(size_t)(d0 + ty + i * 8) * TT + t0 + tx] = tile[tx][ty + i * 8];
}

// ---------------------------------------------------------------------------
// RoPE in-place over a column slice of bf16 QKV. cos/sin fp32 (T x 64).
// ---------------------------------------------------------------------------
__global__ void rope_k(u16* __restrict__ buf, const float* __restrict__ cosb,
                       const float* __restrict__ sinb, int colbase, int ncshift,
                       int rowstride) {
    size_t gid = (size_t)blockIdx.x * 256 + threadIdx.x;
    size_t e = gid * 8;
    int ncols = 1 << ncshift;
    int row = (int)(e >> ncshift);
    int col = (int)(e & (ncols - 1));
    int i0 = (col & (HD - 1)) >> 1;
    int t = row & (TT - 1);
    u16* p = buf + (size_t)row * rowstride + colbase + col;
    union { uint4 v; u16 u[8]; } d, o;
    d.v = *(const uint4*)p;
    float4 c4 = *(const float4*)(cosb + t * 64 + i0);
    float4 s4 = *(const float4*)(sinb + t * 64 + i0);
    float cc[4] = {c4.x, c4.y, c4.z, c4.w};
    float ss[4] = {s4.x, s4.y, s4.z, s4.w};
#pragma unroll
    for (int k = 0; k < 4; k++) {
        float re = b2f(d.u[2 * k]), im = b2f(d.u[2 * k + 1]);
        o.u[2 * k]     = f2b(re * cc[k] - im * ss[k]);
        o.u[2 * k + 1] = f2b(re * ss[k] + im * cc[k]);
    }
    *(uint4*)p = o.v;
}

// ---------------------------------------------------------------------------
// Causal flash attention v3: v2 + double-buffered K/V staging (prefetch tile
// kt+1 during compute of kt -> barrier's vmcnt(0) drains an already-landed
// load) + exp2-domain softmax (1 FMA + 1 v_exp per score) + v_perm P-pack.
// S^T = K·Q^T (Q frags in registers); wave-local softmax; PV from V^T.
// ---------------------------------------------------------------------------
#define PSTR 72
__global__ __launch_bounds__(256, 2)
void attn(const u16* __restrict__ QKV, const u16* __restrict__ Vt,
          u16* __restrict__ O) {
    const int g = blockIdx.x;       // pair index 0..15
    const int h = blockIdx.y;       // head
    const int b = blockIdx.z;       // batch
    const int kvh = h >> 2;
    const int tid = threadIdx.x, w = tid >> 6, lane = tid & 63;
    const int quad = lane >> 4, l16 = lane & 15;

    __shared__ __align__(16) u16 Ks[2][64 * 128];   // [key][16 chunks] sw: c^(key&15)
    __shared__ __align__(16) u16 Vs[2][128 * 64];   // [d][8 chunks]    sw: c^(d&7)
    __shared__ __align__(16) u16 Ps[4][16 * PSTR];  // wave-private [q=l16][64 keys]

    const u16* Kbase = QKV + (size_t)b * TT * 3072 + 2048 + kvh * HD;
    const u16* Vbase = Vt + (size_t)(b * 4 + kvh) * HD * TT;
    const float Cl = 0.12753102474f;  // (1/sqrt(128)) * log2(e)

    auto stage = [&](int kt, int bb) {
#pragma unroll
        for (int i = 0; i < 4; i++) {
            int n = i * 256 + w * 64 + lane;
            int r = n >> 4, c = (n & 15) ^ (r & 15);
            gl_lds16(Kbase + (size_t)(kt * 64 + r) * 3072 + c * 8,
                     &Ks[bb][(i * 256 + w * 64) * 8]);
        }
#pragma unroll
        for (int i = 0; i < 4; i++) {
            int n = i * 256 + w * 64 + lane;
            int d = n >> 3, c = (n & 7) ^ (d & 7);
            gl_lds16(Vbase + (size_t)d * TT + kt * 64 + c * 8,
                     &Vs[bb][(i * 256 + w * 64) * 8]);
        }
    };

    for (int ph = 0; ph < 2; ph++) {
        const int qb = ph ? (31 - g) : g;
        __syncthreads();  // previous phase fully done before re-staging buf 0
        stage(0, 0);

        // Q fragments to registers (B-layout: lane l16 = q-row, quad*8+j = k)
        const u16* Qrow = QKV + ((size_t)b * TT + qb * 64 + w * 16 + l16) * 3072 + h * HD;
        short8 qf[4];
#pragma unroll
        for (int ks = 0; ks < 4; ks++)
            qf[ks] = *(const short8*)(Qrow + ks * 32 + quad * 8);

        float4_t o[8];
#pragma unroll
        for (int i = 0; i < 8; i++) o[i] = (float4_t){0.f, 0.f, 0.f, 0.f};
        float mi = -1e30f, li = 0.f;
        const int qg = qb * 64 + w * 16 + l16;  // this lane's q-row (S^T col)

        for (int kt = 0; kt <= qb; kt++) {
            const int cur = kt & 1;
            __syncthreads();                       // drains stage(kt)
            if (kt < qb) stage(kt + 1, cur ^ 1);   // prefetch under compute

            // S^T = K·Q^T : D[key][q], 64 keys x 16 q (raw logits)
            float4_t st[4];
#pragma unroll
            for (int nt = 0; nt < 4; nt++) st[nt] = (float4_t){0.f, 0.f, 0.f, 0.f};
#pragma unroll
            for (int ks = 0; ks < 4; ks++) {
                short8 af[4];
#pragma unroll
                for (int nt = 0; nt < 4; nt++)
                    af[nt] = *(const short8*)&Ks[cur][((nt * 16 + l16) * 16 +
                                                      ((ks * 4 + quad) ^ l16)) * 8];
#pragma unroll
                for (int nt = 0; nt < 4; nt++)
                    st[nt] = __builtin_amdgcn_mfma_f32_16x16x32_bf16(
                        af[nt], qf[ks], st[nt], 0, 0, 0);
            }

            // causal mask only on (block-uniform) diagonal tile
            if (kt == qb) {
#pragma unroll
                for (int nt = 0; nt < 4; nt++)
#pragma unroll
                    for (int r = 0; r < 4; r++) {
                        int key = kt * 64 + nt * 16 + quad * 4 + r;
                        if (key > qg) st[nt][r] = -3e38f;
                    }
            }
            float pm = -3e38f;
#pragma unroll
            for (int nt = 0; nt < 4; nt++)
#pragma unroll
                for (int r = 0; r < 4; r++) pm = fmaxf(pm, st[nt][r]);
            pm = fmaxf(pm, __shfl_xor(pm, 16, 64));
            pm = fmaxf(pm, __shfl_xor(pm, 32, 64));
            float mnew = fmaxf(mi, pm);
            float alpha = __builtin_amdgcn_exp2f((mi - mnew) * Cl);
            mi = mnew;
            const float mC = mnew * Cl;
            float rs = 0.f;
#pragma unroll
            for (int nt = 0; nt < 4; nt++)
#pragma unroll
                for (int r = 0; r < 4; r++) {
                    float e = __builtin_amdgcn_exp2f(fmaf(st[nt][r], Cl, -mC));
                    st[nt][r] = e;
                    rs += e;
                }
            rs += __shfl_xor(rs, 16, 64);
            rs += __shfl_xor(rs, 32, 64);
            li = li * alpha + rs;

            // P -> wave-private strip (truncation-pack via v_perm, b64 writes)
#pragma unroll
            for (int nt = 0; nt < 4; nt++) {
                uint2 pk;
                pk.x = __builtin_amdgcn_perm(fbits(st[nt][1]), fbits(st[nt][0]), 0x07060302u);
                pk.y = __builtin_amdgcn_perm(fbits(st[nt][3]), fbits(st[nt][2]), 0x07060302u);
                *(uint2*)&Ps[w][l16 * PSTR + nt * 16 + quad * 4] = pk;
            }
            // rescale O (o rows are q=quad*4+r -> fetch alpha from lane q)
            float a_o[4];
#pragma unroll
            for (int r = 0; r < 4; r++) a_o[r] = __shfl(alpha, quad * 4 + r, 64);
#pragma unroll
            for (int n2 = 0; n2 < 8; n2++)
#pragma unroll
                for (int r = 0; r < 4; r++) o[n2][r] *= a_o[r];

            // O += P·V : A-frag from strip (m=q=l16), B-frag = V^T rows (n=d)
#pragma unroll
            for (int ks2 = 0; ks2 < 2; ks2++) {
                short8 ap = *(const short8*)&Ps[w][l16 * PSTR + ks2 * 32 + quad * 8];
#pragma unroll
                for (int n2 = 0; n2 < 8; n2++) {
                    short8 bv = *(const short8*)&Vs[cur][((n2 * 16 + l16) * 8 +
                                                         ((ks2 * 4 + quad) ^ (l16 & 7))) * 8];
                    o[n2] = __builtin_amdgcn_mfma_f32_16x16x32_bf16(ap, bv, o[n2], 0, 0, 0);
                }
            }
        }

        // epilogue: rows quad*4+r of this wave's 16; li from lane q
        float l_o[4];
#pragma unroll
        for (int r = 0; r < 4; r++) l_o[r] = __shfl(li, quad * 4 + r, 64);
        u16* Ob2 = O + ((size_t)b * TT + qb * 64 + w * 16) * TDIM + h * HD;
#pragma unroll
        for (int n2 = 0; n2 < 8; n2++)
#pragma unroll
            for (int r = 0; r < 4; r++)
                Ob2[(size_t)(quad * 4 + r) * TDIM + n2 * 16 + l16] =
                    f2b(o[n2][r] / l_o[r]);
    }
}

// ---------------------------------------------------------------------------
extern "C" void kernel_launch(void* const* d_in, const int* in_sizes, int n_in,
                              void* d_out, int out_size, void* d_ws, size_t ws_size,
                              hipStream_t stream) {
    const float* x  = (const float*)d_in[0];
    const float* fc = (const float*)d_in[1];
    const float* fs = (const float*)d_in[2];
    const float* wq = (const float*)d_in[3];
    const float* wk = (const float*)d_in[4];
    const float* wv = (const float*)d_in[5];
    const float* wo = (const float*)d_in[6];
    float* out = (float*)d_out;

    char* ws = (char*)d_ws;
    size_t off = 0;
    auto alloc = [&](size_t bytes) -> void* {
        void* p = ws + off;
        off += (bytes + 255) & ~(size_t)255;
        return p;
    };
    u16* xb  = (u16*)alloc((size_t)4096 * 2048 * 2);  // x in bf16
    u16* WT  = (u16*)alloc((size_t)3072 * 2048 * 2);  // [wqT|wkT|wvT] N x K bf16
    u16* woT = (u16*)alloc((size_t)2048 * 2048 * 2);
    u16* QKV = (u16*)alloc((size_t)4096 * 3072 * 2);  // [Q|K|V] fused bf16
    u16* Vtb = (u16*)alloc((size_t)4096 * 512 * 2);   // V^T per (b,kv): [d][t]
    u16* Ob  = (u16*)alloc((size_t)4096 * 2048 * 2);  // attention output bf16

    dim3 blk(256);
    cvt_bf16<<<dim3(8192), blk, 0, stream>>>(x, xb);
    cvt_transpose<<<dim3(64, 64), blk, 0, stream>>>(wq, WT, 2048, 2048);
    cvt_transpose<<<dim3(16, 64), blk, 0, stream>>>(wk, WT + (size_t)2048 * 2048, 2048, 512);
    cvt_transpose<<<dim3(16, 64), blk, 0, stream>>>(wv, WT + (size_t)2560 * 2048, 2048, 512);
    cvt_transpose<<<dim3(64, 64), blk, 0, stream>>>(wo, woT, 2048, 2048);
    gemm_bt<false><<<dim3(24, 32), blk, 0, stream>>>(xb, WT, QKV, 4096, 3072, 2048);
    rope_k<<<dim3(4096), blk, 0, stream>>>(QKV, fc, fs, 0, 11, 3072);
    rope_k<<<dim3(1024), blk, 0, stream>>>(QKV, fc, fs, 2048, 9, 3072);
    transpose_v<<<dim3(64, 4, 8), blk, 0, stream>>>(QKV, Vtb);
    attn<<<dim3(16, 16, 2), blk, 0, stream>>>(QKV, Vtb, Ob);
    gemm_bt<true><<<dim3(16, 32), blk, 0, stream>>>(Ob, woT, out, 4096, 2048, 2048);
}